// Round 4
// baseline (400.188 us; speedup 1.0000x reference)
//
#include <hip/hip_runtime.h>
#include <math.h>

#define T_LEN 32768
#define D_DIM 1024
#define LD 4
#define H_DIM 6
#define WARM 20

#define LOG2PI 1.8378770664093453f

#define ENC_ROWS 64     // rows per block
#define ENC_KW 256      // k per wave
#define ENC_KT 32       // k per tile
#define LDS_STRIDE 36   // floats per row in LDS (bank-conflict-free: 36%32=4)

__device__ __forceinline__ float frcp(float x) {
    float r = __builtin_amdgcn_rcpf(x);
    return r * (2.0f - x * r);
}

// Cholesky of 4x4 SPD S (row-major). Fills lower cL, invd[j] = 1/cL[j][j].
__device__ __forceinline__ void chol4(const float* S, float* cL, float* invd) {
#pragma unroll
    for (int j = 0; j < 4; ++j) {
        float d = S[j * 4 + j];
#pragma unroll
        for (int k = 0; k < j; ++k) d -= cL[j * 4 + k] * cL[j * 4 + k];
        float c = sqrtf(d);
        cL[j * 4 + j] = c;
        float id = frcp(c);
        invd[j] = id;
#pragma unroll
        for (int i = j + 1; i < 4; ++i) {
            float v = S[i * 4 + j];
#pragma unroll
            for (int k = 0; k < j; ++k) v -= cL[i * 4 + k] * cL[j * 4 + k];
            cL[i * 4 + j] = v * id;
        }
    }
}

// X = S^{-1} B  (4 RHS = columns of B), S = cL cL^T
__device__ __forceinline__ void chosolve4(const float* cL, const float* invd,
                                          const float* B, float* X) {
#pragma unroll
    for (int c = 0; c < 4; ++c) {
        float y0 = B[0 * 4 + c] * invd[0];
        float y1 = (B[1 * 4 + c] - cL[4] * y0) * invd[1];
        float y2 = (B[2 * 4 + c] - cL[8] * y0 - cL[9] * y1) * invd[2];
        float y3 = (B[3 * 4 + c] - cL[12] * y0 - cL[13] * y1 - cL[14] * y2) * invd[3];
        float x3 = y3 * invd[3];
        float x2 = (y2 - cL[14] * x3) * invd[2];
        float x1 = (y1 - cL[9] * x2 - cL[13] * x3) * invd[1];
        float x0 = (y0 - cL[4] * x1 - cL[8] * x2 - cL[12] * x3) * invd[0];
        X[0 * 4 + c] = x0; X[1 * 4 + c] = x1; X[2 * 4 + c] = x2; X[3 * 4 + c] = x3;
    }
}

__device__ __forceinline__ void mm4(const float* A, const float* B, float* C) {
#pragma unroll
    for (int i = 0; i < 4; ++i)
#pragma unroll
        for (int j = 0; j < 4; ++j) {
            float s = 0.f;
#pragma unroll
            for (int k = 0; k < 4; ++k) s += A[i * 4 + k] * B[k * 4 + j];
            C[i * 4 + j] = s;
        }
}

// ---------------- encoder: row-per-lane, K split over 4 waves, LDS transpose
__global__ __launch_bounds__(256) void encoder_kernel(
    const float* __restrict__ x, const float* __restrict__ W1, const float* __restrict__ b1,
    const float* __restrict__ Wmu, const float* __restrict__ bmu,
    const float* __restrict__ Wlv, const float* __restrict__ blv,
    float* __restrict__ mu_o, float* __restrict__ sig_o) {
    __shared__ __align__(16) float lds[4 * ENC_ROWS * LDS_STRIDE];
    __shared__ float red[4 * ENC_ROWS * H_DIM];

    const int tid = threadIdx.x;
    const int w = tid >> 6;          // wave id: k-quarter
    const int l = tid & 63;          // lane: row within block
    const int R0 = blockIdx.x * ENC_ROWS;
    const int k0w = w * ENC_KW;
    float* wlds = lds + w * (ENC_ROWS * LDS_STRIDE);

    const int rsub = l >> 3;         // 0..7
    const int f4 = l & 7;            // float4 slot within 32-float segment

    const float4* x4 = reinterpret_cast<const float4*>(x);

    float4 buf[8];
    // prefetch tile 0: rows p*8+rsub, 128B segments (coalesced per 8 lanes)
#pragma unroll
    for (int p = 0; p < 8; ++p) {
        int r = p * 8 + rsub;
        buf[p] = x4[(size_t)(R0 + r) * 256 + (k0w >> 2) + f4];
    }

    float acc[H_DIM] = {0.f, 0.f, 0.f, 0.f, 0.f, 0.f};

    for (int t = 0; t < ENC_KW / ENC_KT; ++t) {
        // write tile t to LDS (conflict-free: banks 4*(rsub+f4) cover all 32 exactly 8x)
#pragma unroll
        for (int p = 0; p < 8; ++p) {
            int r = p * 8 + rsub;
            *reinterpret_cast<float4*>(&wlds[r * LDS_STRIDE + f4 * 4]) = buf[p];
        }
        // prefetch tile t+1
        if (t < ENC_KW / ENC_KT - 1) {
            const int k0 = k0w + (t + 1) * ENC_KT;
#pragma unroll
            for (int p = 0; p < 8; ++p) {
                int r = p * 8 + rsub;
                buf[p] = x4[(size_t)(R0 + r) * 256 + (k0 >> 2) + f4];
            }
        }
        const int kbase = k0w + t * ENC_KT;
        // lane l = row l; reads banks 4*(l+j4) -> conflict-free; W1 index wave-uniform -> scalar loads
#pragma unroll
        for (int j4 = 0; j4 < 8; ++j4) {
            float4 xv = *reinterpret_cast<const float4*>(&wlds[l * LDS_STRIDE + j4 * 4]);
            const float* wrow = W1 + (size_t)(kbase + j4 * 4) * H_DIM;
            float xe[4] = {xv.x, xv.y, xv.z, xv.w};
#pragma unroll
            for (int e = 0; e < 4; ++e)
#pragma unroll
                for (int j = 0; j < H_DIM; ++j)
                    acc[j] += xe[e] * wrow[e * H_DIM + j];
        }
    }

    // cross-wave reduce (4 partials per row)
#pragma unroll
    for (int j = 0; j < H_DIM; ++j) red[(w * ENC_ROWS + l) * H_DIM + j] = acc[j];
    __syncthreads();
    if (w == 0) {
        float s[H_DIM];
#pragma unroll
        for (int j = 0; j < H_DIM; ++j)
            s[j] = red[l * H_DIM + j] + red[(ENC_ROWS + l) * H_DIM + j] +
                   red[(2 * ENC_ROWS + l) * H_DIM + j] + red[(3 * ENC_ROWS + l) * H_DIM + j];
        float h[H_DIM];
#pragma unroll
        for (int j = 0; j < H_DIM; ++j) h[j] = fmaxf(s[j] + b1[j], 0.f);
        float muv[4], lvv[4];
#pragma unroll
        for (int i = 0; i < 4; ++i) { muv[i] = bmu[i]; lvv[i] = blv[i]; }
#pragma unroll
        for (int j = 0; j < H_DIM; ++j)
#pragma unroll
            for (int i = 0; i < 4; ++i) {
                muv[i] += h[j] * Wmu[j * LD + i];
                lvv[i] += h[j] * Wlv[j * LD + i];
            }
        reinterpret_cast<float4*>(mu_o)[R0 + l] = make_float4(muv[0], muv[1], muv[2], muv[3]);
        float4 sg;
        sg.x = expf(0.5f * lvv[0]); sg.y = expf(0.5f * lvv[1]);
        sg.z = expf(0.5f * lvv[2]); sg.w = expf(0.5f * lvv[3]);
        reinterpret_cast<float4*>(sig_o)[R0 + l] = sg;
    }
}

// ---------------- filter: per-timestep thread, warm-started WARM steps back
__global__ __launch_bounds__(64) void filter_kernel(
    const float* __restrict__ mu, const float* __restrict__ sigma,
    const float* __restrict__ Ain, const float* __restrict__ b_dyn,
    const float* __restrict__ qp,
    float* __restrict__ fm, float* __restrict__ fP,
    float* __restrict__ pm, float* __restrict__ pP, float* __restrict__ ll_out) {
    int t_own = blockIdx.x * blockDim.x + threadIdx.x;

    float a[16], b[4];
#pragma unroll
    for (int i = 0; i < 16; ++i) a[i] = Ain[i];
#pragma unroll
    for (int i = 0; i < 4; ++i) b[i] = b_dyn[i];

    float Lm[16];
#pragma unroll
    for (int i = 0; i < 16; ++i) Lm[i] = 0.f;
    Lm[0] = expf(qp[0]);
    Lm[4] = qp[1];  Lm[5] = expf(qp[2]);
    Lm[8] = qp[3];  Lm[9] = qp[4];  Lm[10] = expf(qp[5]);
    Lm[12] = qp[6]; Lm[13] = qp[7]; Lm[14] = qp[8]; Lm[15] = expf(qp[9]);
    float Q[16];
#pragma unroll
    for (int i = 0; i < 4; ++i)
#pragma unroll
        for (int j = 0; j < 4; ++j) {
            float s = 0.f;
#pragma unroll
            for (int k = 0; k < 4; ++k) s += Lm[i * 4 + k] * Lm[j * 4 + k];
            Q[i * 4 + j] = s;
        }

    int start = t_own - WARM;
    if (start < 0) start = 0;

    float m[4] = {0.f, 0.f, 0.f, 0.f};
    float P[16];
#pragma unroll
    for (int i = 0; i < 16; ++i) P[i] = 0.f;
    P[0] = P[5] = P[10] = P[15] = 1.f;

    const float4* mu4 = reinterpret_cast<const float4*>(mu);
    const float4* sg4 = reinterpret_cast<const float4*>(sigma);

    float mp[4], Pp[16], mf[4], Pf[16], cL[16], invd[4], innov[4];

    for (int t = start; t <= t_own; ++t) {
        float4 yv = mu4[t];
        float4 rv = sg4[t];
        float y[4] = {yv.x, yv.y, yv.z, yv.w};
#pragma unroll
        for (int i = 0; i < 4; ++i) {
            float s0 = b[i];
#pragma unroll
            for (int k = 0; k < 4; ++k) s0 += a[i * 4 + k] * m[k];
            mp[i] = s0;
        }
        float AP[16];
        mm4(a, P, AP);
#pragma unroll
        for (int i = 0; i < 4; ++i)
#pragma unroll
            for (int j = 0; j < 4; ++j) {
                float s0 = Q[i * 4 + j];
#pragma unroll
                for (int k = 0; k < 4; ++k) s0 += AP[i * 4 + k] * a[j * 4 + k];
                Pp[i * 4 + j] = s0;
            }
        float S[16];
#pragma unroll
        for (int i = 0; i < 16; ++i) S[i] = Pp[i];
        S[0] += rv.x; S[5] += rv.y; S[10] += rv.z; S[15] += rv.w;
        chol4(S, cL, invd);
        float X[16];
        chosolve4(cL, invd, Pp, X);
#pragma unroll
        for (int i = 0; i < 4; ++i) innov[i] = y[i] - mp[i];
#pragma unroll
        for (int i = 0; i < 4; ++i) {
            float s0 = mp[i];
#pragma unroll
            for (int k = 0; k < 4; ++k) s0 += X[k * 4 + i] * innov[k];
            mf[i] = s0;
        }
        float M[16];
#pragma unroll
        for (int i = 0; i < 4; ++i)
#pragma unroll
            for (int j = 0; j < 4; ++j) {
                float s0 = Pp[i * 4 + j];
#pragma unroll
                for (int k = 0; k < 4; ++k) s0 -= X[k * 4 + i] * Pp[k * 4 + j];
                M[i * 4 + j] = s0;
            }
#pragma unroll
        for (int i = 0; i < 4; ++i)
#pragma unroll
            for (int j = 0; j < 4; ++j)
                Pf[i * 4 + j] = 0.5f * (M[i * 4 + j] + M[j * 4 + i]);
#pragma unroll
        for (int i = 0; i < 4; ++i) m[i] = mf[i];
#pragma unroll
        for (int i = 0; i < 16; ++i) P[i] = Pf[i];
    }

    float w0 = innov[0] * invd[0];
    float w1 = (innov[1] - cL[4] * w0) * invd[1];
    float w2 = (innov[2] - cL[8] * w0 - cL[9] * w1) * invd[2];
    float w3 = (innov[3] - cL[12] * w0 - cL[13] * w1 - cL[14] * w2) * invd[3];
    float wsq = w0 * w0 + w1 * w1 + w2 * w2 + w3 * w3;
    float proddiag = cL[0] * cL[5] * cL[10] * cL[15];
    float ll_term = -0.5f * (4.f * LOG2PI + wsq) - logf(proddiag);

    float4* fm4 = reinterpret_cast<float4*>(fm);
    float4* pm4 = reinterpret_cast<float4*>(pm);
    float4* fP4 = reinterpret_cast<float4*>(fP);
    float4* pP4 = reinterpret_cast<float4*>(pP);
    fm4[t_own] = make_float4(mf[0], mf[1], mf[2], mf[3]);
    pm4[t_own] = make_float4(mp[0], mp[1], mp[2], mp[3]);
#pragma unroll
    for (int q = 0; q < 4; ++q) {
        fP4[t_own * 4 + q] = make_float4(Pf[q * 4 + 0], Pf[q * 4 + 1], Pf[q * 4 + 2], Pf[q * 4 + 3]);
        pP4[t_own * 4 + q] = make_float4(Pp[q * 4 + 0], Pp[q * 4 + 1], Pp[q * 4 + 2], Pp[q * 4 + 3]);
    }

#pragma unroll
    for (int off = 32; off; off >>= 1)
        ll_term += __shfl_xor(ll_term, off, 64);
    if ((threadIdx.x & 63) == 0) atomicAdd(ll_out, ll_term);
}

// ---------------- smoother (+ sampling z): per-timestep thread
__global__ __launch_bounds__(64) void smoother_kernel(
    const float* __restrict__ fm, const float* __restrict__ fP,
    const float* __restrict__ pm, const float* __restrict__ pP,
    const float* __restrict__ Ain, const float* __restrict__ eps,
    float* __restrict__ sm, float* __restrict__ sP, float* __restrict__ z) {
    int c = blockIdx.x * blockDim.x + threadIdx.x;

    const float4* fm4 = reinterpret_cast<const float4*>(fm);
    const float4* fP4 = reinterpret_cast<const float4*>(fP);
    const float4* pm4 = reinterpret_cast<const float4*>(pm);
    const float4* pP4 = reinterpret_cast<const float4*>(pP);
    const float4* ep4 = reinterpret_cast<const float4*>(eps);
    float4* sm4 = reinterpret_cast<float4*>(sm);
    float4* sP4 = reinterpret_cast<float4*>(sP);
    float4* z4 = reinterpret_cast<float4*>(z);

    if (c == T_LEN - 1) {
        int t = T_LEN - 1;
        float4 mt = fm4[t];
        float Pt[16];
#pragma unroll
        for (int q = 0; q < 4; ++q) {
            float4 v = fP4[t * 4 + q];
            Pt[q * 4 + 0] = v.x; Pt[q * 4 + 1] = v.y; Pt[q * 4 + 2] = v.z; Pt[q * 4 + 3] = v.w;
        }
        sm4[t] = mt;
#pragma unroll
        for (int q = 0; q < 4; ++q)
            sP4[t * 4 + q] = make_float4(Pt[q * 4 + 0], Pt[q * 4 + 1], Pt[q * 4 + 2], Pt[q * 4 + 3]);
        float Sz[16];
#pragma unroll
        for (int i = 0; i < 16; ++i) Sz[i] = Pt[i];
        Sz[0] += 1e-6f; Sz[5] += 1e-6f; Sz[10] += 1e-6f; Sz[15] += 1e-6f;
        float cLt[16], invdt[4];
        chol4(Sz, cLt, invdt);
        float4 ev = ep4[t];
        float e[4] = {ev.x, ev.y, ev.z, ev.w};
        float zz[4];
        zz[0] = mt.x + cLt[0] * e[0];
        zz[1] = mt.y + cLt[4] * e[0] + cLt[5] * e[1];
        zz[2] = mt.z + cLt[8] * e[0] + cLt[9] * e[1] + cLt[10] * e[2];
        zz[3] = mt.w + cLt[12] * e[0] + cLt[13] * e[1] + cLt[14] * e[2] + cLt[15] * e[3];
        z4[t] = make_float4(zz[0], zz[1], zz[2], zz[3]);
        return;
    }

    float a[16];
#pragma unroll
    for (int i = 0; i < 16; ++i) a[i] = Ain[i];

    int t_init = c + WARM;
    if (t_init > T_LEN - 2) t_init = T_LEN - 2;

    float ms[4], Ps[16];
    {
        int ti = t_init + 1;
        float4 mv = fm4[ti];
        ms[0] = mv.x; ms[1] = mv.y; ms[2] = mv.z; ms[3] = mv.w;
#pragma unroll
        for (int q = 0; q < 4; ++q) {
            float4 v = fP4[ti * 4 + q];
            Ps[q * 4 + 0] = v.x; Ps[q * 4 + 1] = v.y; Ps[q * 4 + 2] = v.z; Ps[q * 4 + 3] = v.w;
        }
    }

    for (int t = t_init; t >= c; --t) {
        float4 mfv = fm4[t];
        float mf_[4] = {mfv.x, mfv.y, mfv.z, mfv.w};
        float Pf[16];
#pragma unroll
        for (int q = 0; q < 4; ++q) {
            float4 v = fP4[t * 4 + q];
            Pf[q * 4 + 0] = v.x; Pf[q * 4 + 1] = v.y; Pf[q * 4 + 2] = v.z; Pf[q * 4 + 3] = v.w;
        }
        float4 pmv = pm4[t + 1];
        float mpn[4] = {pmv.x, pmv.y, pmv.z, pmv.w};
        float Ppn[16];
#pragma unroll
        for (int q = 0; q < 4; ++q) {
            float4 v = pP4[(t + 1) * 4 + q];
            Ppn[q * 4 + 0] = v.x; Ppn[q * 4 + 1] = v.y; Ppn[q * 4 + 2] = v.z; Ppn[q * 4 + 3] = v.w;
        }
        float cL[16], invd[4];
        chol4(Ppn, cL, invd);
        float B[16];
        mm4(a, Pf, B);
        float X[16];
        chosolve4(cL, invd, B, X);
        float dm[4];
#pragma unroll
        for (int i = 0; i < 4; ++i) dm[i] = ms[i] - mpn[i];
        float msn[4];
#pragma unroll
        for (int i = 0; i < 4; ++i) {
            float s0 = mf_[i];
#pragma unroll
            for (int k = 0; k < 4; ++k) s0 += X[k * 4 + i] * dm[k];
            msn[i] = s0;
        }
        float DP[16];
#pragma unroll
        for (int i = 0; i < 16; ++i) DP[i] = Ps[i] - Ppn[i];
        float GD[16];
#pragma unroll
        for (int i = 0; i < 4; ++i)
#pragma unroll
            for (int j = 0; j < 4; ++j) {
                float s0 = 0.f;
#pragma unroll
                for (int k = 0; k < 4; ++k) s0 += X[k * 4 + i] * DP[k * 4 + j];
                GD[i * 4 + j] = s0;
            }
        float M[16];
#pragma unroll
        for (int i = 0; i < 4; ++i)
#pragma unroll
            for (int j = 0; j < 4; ++j) {
                float s0 = Pf[i * 4 + j];
#pragma unroll
                for (int k = 0; k < 4; ++k) s0 += GD[i * 4 + k] * X[k * 4 + j];
                M[i * 4 + j] = s0;
            }
#pragma unroll
        for (int i = 0; i < 4; ++i)
#pragma unroll
            for (int j = 0; j < 4; ++j)
                Ps[i * 4 + j] = 0.5f * (M[i * 4 + j] + M[j * 4 + i]);
#pragma unroll
        for (int i = 0; i < 4; ++i) ms[i] = msn[i];
    }

    sm4[c] = make_float4(ms[0], ms[1], ms[2], ms[3]);
#pragma unroll
    for (int q = 0; q < 4; ++q)
        sP4[c * 4 + q] = make_float4(Ps[q * 4 + 0], Ps[q * 4 + 1], Ps[q * 4 + 2], Ps[q * 4 + 3]);
    float Sz[16];
#pragma unroll
    for (int i = 0; i < 16; ++i) Sz[i] = Ps[i];
    Sz[0] += 1e-6f; Sz[5] += 1e-6f; Sz[10] += 1e-6f; Sz[15] += 1e-6f;
    float cz[16], izd[4];
    chol4(Sz, cz, izd);
    float4 ev = ep4[c];
    float e[4] = {ev.x, ev.y, ev.z, ev.w};
    float zz[4];
    zz[0] = ms[0] + cz[0] * e[0];
    zz[1] = ms[1] + cz[4] * e[0] + cz[5] * e[1];
    zz[2] = ms[2] + cz[8] * e[0] + cz[9] * e[1] + cz[10] * e[2];
    zz[3] = ms[3] + cz[12] * e[0] + cz[13] * e[1] + cz[14] * e[2] + cz[15] * e[3];
    z4[c] = make_float4(zz[0], zz[1], zz[2], zz[3]);
}

// ---------------- decoder: wave-per-row, Wd2 hoisted in registers, grid-stride
__global__ __launch_bounds__(256) void decoder_kernel(
    const float* __restrict__ z, const float* __restrict__ Wd1, const float* __restrict__ bd1,
    const float* __restrict__ Wd2, const float* __restrict__ bd2,
    float* __restrict__ xr) {
    const int l = threadIdx.x & 63;
    const int wid = blockIdx.x * 4 + (threadIdx.x >> 6);   // 0..2047
    const int NWAVES = 2048;

    // lane owns float4 column-groups {c*64 + l : c=0..3} -> contiguous wave stores
    float4 wd[H_DIM][4];
#pragma unroll
    for (int j = 0; j < H_DIM; ++j) {
        const float4* wr = reinterpret_cast<const float4*>(Wd2 + (size_t)j * D_DIM);
#pragma unroll
        for (int cc = 0; cc < 4; ++cc) wd[j][cc] = wr[cc * 64 + l];
    }
    float4 bv[4];
    {
        const float4* br = reinterpret_cast<const float4*>(bd2);
#pragma unroll
        for (int cc = 0; cc < 4; ++cc) bv[cc] = br[cc * 64 + l];
    }
    float wd1[LD * H_DIM], b1v[H_DIM];
#pragma unroll
    for (int i = 0; i < LD * H_DIM; ++i) wd1[i] = Wd1[i];
#pragma unroll
    for (int j = 0; j < H_DIM; ++j) b1v[j] = bd1[j];

    const float4* z4 = reinterpret_cast<const float4*>(z);

    for (int row = wid; row < T_LEN; row += NWAVES) {
        float4 zv = z4[row];
        float h[H_DIM];
#pragma unroll
        for (int j = 0; j < H_DIM; ++j) {
            float s = b1v[j] + zv.x * wd1[0 * H_DIM + j] + zv.y * wd1[1 * H_DIM + j] +
                      zv.z * wd1[2 * H_DIM + j] + zv.w * wd1[3 * H_DIM + j];
            h[j] = fmaxf(s, 0.f);
        }
        float4* out4 = reinterpret_cast<float4*>(xr + (size_t)row * D_DIM);
#pragma unroll
        for (int cc = 0; cc < 4; ++cc) {
            float4 o = bv[cc];
#pragma unroll
            for (int j = 0; j < H_DIM; ++j) {
                o.x += h[j] * wd[j][cc].x;
                o.y += h[j] * wd[j][cc].y;
                o.z += h[j] * wd[j][cc].z;
                o.w += h[j] * wd[j][cc].w;
            }
            out4[cc * 64 + l] = o;
        }
    }
}

extern "C" void kernel_launch(void* const* d_in, const int* in_sizes, int n_in,
                              void* d_out, int out_size, void* d_ws, size_t ws_size,
                              hipStream_t stream) {
    const float* x    = (const float*)d_in[0];
    const float* eps  = (const float*)d_in[1];
    const float* W1   = (const float*)d_in[2];
    const float* b1   = (const float*)d_in[3];
    const float* Wmu  = (const float*)d_in[4];
    const float* bmu  = (const float*)d_in[5];
    const float* Wlv  = (const float*)d_in[6];
    const float* blv  = (const float*)d_in[7];
    const float* Wd1  = (const float*)d_in[8];
    const float* bd1  = (const float*)d_in[9];
    const float* Wd2  = (const float*)d_in[10];
    const float* bd2  = (const float*)d_in[11];
    const float* A    = (const float*)d_in[12];
    const float* bdyn = (const float*)d_in[13];
    const float* qp   = (const float*)d_in[14];

    float* out = (float*)d_out;
    size_t off = 0;
    float* xr_o  = out + off; off += (size_t)T_LEN * D_DIM;   // x_recon
    float* z_o   = out + off; off += (size_t)T_LEN * LD;      // z
    float* mu_o  = out + off; off += (size_t)T_LEN * LD;      // mu
    float* sig_o = out + off; off += (size_t)T_LEN * LD;      // sigma
    float* fm_o  = out + off; off += (size_t)T_LEN * LD;      // fm
    float* fP_o  = out + off; off += (size_t)T_LEN * LD * LD; // fP
    float* sm_o  = out + off; off += (size_t)T_LEN * LD;      // sm
    float* sP_o  = out + off; off += (size_t)T_LEN * LD * LD; // sP
    float* pm_o  = out + off; off += (size_t)T_LEN * LD;      // pm
    float* pP_o  = out + off; off += (size_t)T_LEN * LD * LD; // pP
    float* ll_o  = out + off;                                  // marginal_loglik

    hipMemsetAsync(ll_o, 0, sizeof(float), stream);

    encoder_kernel<<<T_LEN / ENC_ROWS, 256, 0, stream>>>(x, W1, b1, Wmu, bmu, Wlv, blv, mu_o, sig_o);
    filter_kernel<<<T_LEN / 64, 64, 0, stream>>>(mu_o, sig_o, A, bdyn, qp, fm_o, fP_o, pm_o, pP_o, ll_o);
    smoother_kernel<<<T_LEN / 64, 64, 0, stream>>>(fm_o, fP_o, pm_o, pP_o, A, eps, sm_o, sP_o, z_o);
    decoder_kernel<<<512, 256, 0, stream>>>(z_o, Wd1, bd1, Wd2, bd2, xr_o);
}